// Round 2
// baseline (226.736 us; speedup 1.0000x reference)
//
#include <hip/hip_runtime.h>
#include <hip/hip_bf16.h>

typedef short bf16x8 __attribute__((ext_vector_type(8)));
typedef float f32x4 __attribute__((ext_vector_type(4)));
typedef unsigned short u16;
typedef unsigned int u32;

__device__ __forceinline__ u16 f2b(float v) {
    u32 u = __float_as_uint(v);
    u += 0x7fff + ((u >> 16) & 1);   // round-to-nearest-even
    return (u16)(u >> 16);
}

// ---------------- prep kernels ----------------
__global__ void cast_f32_to_bf16_vec(const float* __restrict__ in, u16* __restrict__ out, int n4) {
    int i = blockIdx.x * blockDim.x + threadIdx.x;
    int stride = gridDim.x * blockDim.x;
    for (; i < n4; i += stride) {
        float4 v = ((const float4*)in)[i];
        ushort4 o;
        o.x = f2b(v.x); o.y = f2b(v.y); o.z = f2b(v.z); o.w = f2b(v.w);
        ((ushort4*)out)[i] = o;
    }
}

// wt[n*K + k] = w[k*N + n]  (f32 -> bf16)
__global__ void cast_transpose(const float* __restrict__ w, u16* __restrict__ wt, int N, int K) {
    int i = blockIdx.x * blockDim.x + threadIdx.x;
    if (i >= N * K) return;
    int n = i / K, k = i - n * K;
    wt[i] = f2b(w[(size_t)k * N + n]);
}

// rpb[h][i][j] = table[rpi[i][j]*6 + h]
__global__ void rpb_gather(const int* __restrict__ rpi, const float* __restrict__ table,
                           float* __restrict__ rpb) {
    int ij = blockIdx.x * blockDim.x + threadIdx.x;  // 65536
    int idx = rpi[ij];
#pragma unroll
    for (int h = 0; h < 6; ++h) rpb[h * 65536 + ij] = table[idx * 6 + h];
}

// ---------------- GEMM: C[M][N] = A[M][192] * Bt[N][192]^T ----------------
// BM=128, BN=64, 8 waves (4x2), wave tile 32x32, full K staged in LDS.
template <bool IS_QKV>
__global__ __launch_bounds__(512) void gemm_k(const u16* __restrict__ A, const u16* __restrict__ Bt,
                                              const float* __restrict__ bias, void* outp, int N,
                                              float qscale) {
    __shared__ u16 lsA[128 * 200];
    __shared__ u16 lsB[64 * 200];
    const int m0 = blockIdx.x * 128;
    const int n0 = blockIdx.y * 64;
    const int tid = threadIdx.x;

    for (int c = tid; c < 128 * 24; c += 512) {
        int r = c / 24, cc = c % 24;
        *(uint4*)&lsA[r * 200 + cc * 8] = *(const uint4*)(A + (size_t)(m0 + r) * 192 + cc * 8);
    }
    for (int c = tid; c < 64 * 24; c += 512) {
        int r = c / 24, cc = c % 24;
        *(uint4*)&lsB[r * 200 + cc * 8] = *(const uint4*)(Bt + (size_t)(n0 + r) * 192 + cc * 8);
    }
    __syncthreads();

    const int l = tid & 63, wv = tid >> 6;
    const int wm = wv >> 1, wn = wv & 1;
    const int lr = l & 15, lg = l >> 4;

    f32x4 acc[2][2] = {};
#pragma unroll
    for (int ks = 0; ks < 6; ++ks) {
        bf16x8 a[2], b[2];
#pragma unroll
        for (int i = 0; i < 2; ++i)
            a[i] = *(const bf16x8*)&lsA[(wm * 32 + i * 16 + lr) * 200 + ks * 32 + lg * 8];
#pragma unroll
        for (int i = 0; i < 2; ++i)
            b[i] = *(const bf16x8*)&lsB[(wn * 32 + i * 16 + lr) * 200 + ks * 32 + lg * 8];
#pragma unroll
        for (int m = 0; m < 2; ++m)
#pragma unroll
            for (int n = 0; n < 2; ++n)
                acc[m][n] = __builtin_amdgcn_mfma_f32_16x16x32_bf16(a[m], b[n], acc[m][n], 0, 0, 0);
    }

#pragma unroll
    for (int m = 0; m < 2; ++m)
#pragma unroll
        for (int n = 0; n < 2; ++n)
#pragma unroll
            for (int j = 0; j < 4; ++j) {
                int gr = m0 + wm * 32 + m * 16 + lg * 4 + j;
                int gc = n0 + wn * 32 + n * 16 + lr;
                float v = acc[m][n][j];
                if (IS_QKV) {
                    if (gc < 192) v *= qscale;
                    v += bias[gc];
                    ((u16*)outp)[(size_t)gr * N + gc] = f2b(v);
                } else {
                    v += bias[gc];
                    ((float*)outp)[(size_t)gr * N + gc] = v;
                }
            }
}

// ---------------- attention ----------------
// block = (window, head, half of 128 q-rows); 8 waves x 16 q-rows.
// S^T layout: mfma(A=K, B=Q) -> lane owns q = lr; kv = nt*16 + lg*4 + j.
__global__ __launch_bounds__(512, 2) void attn_k(const u16* __restrict__ qkv,
                                                 const float* __restrict__ rpb,
                                                 const float* __restrict__ mask,
                                                 u16* __restrict__ out) {
    __shared__ u16 lk[256 * 40];    // K rows, padded stride 40
    __shared__ u16 lvt[32 * 264];   // V transposed [d][np], padded stride 264
    __shared__ u16 lp[8 * 640];     // per-wave P chunk [16 q][40]

    const int b = blockIdx.x;
    const int w = b / 12;
    const int rem = b % 12;
    const int h = rem >> 1, half = rem & 1;
    const int tid = threadIdx.x;

    // stage K (256 rows x 32 d)
    for (int c = tid; c < 256 * 4; c += 512) {
        int j = c >> 2, cc = c & 3;
        size_t g = ((size_t)(w * 256 + j) * 3 + 1) * 192 + h * 32 + cc * 8;
        *(uint4*)&lk[j * 40 + cc * 8] = *(const uint4*)(qkv + g);
    }
    // stage V transposed: thread t covers j = t/2, d = (t&1)*16 .. +16
    {
        int j = tid >> 1, d0 = (tid & 1) * 16;
        size_t g = ((size_t)(w * 256 + j) * 3 + 2) * 192 + h * 32 + d0;
        union { uint4 u; u16 s[8]; } u0, u1;
        u0.u = *(const uint4*)(qkv + g);
        u1.u = *(const uint4*)(qkv + g + 8);
#pragma unroll
        for (int dd = 0; dd < 8; ++dd) {
            lvt[(d0 + dd) * 264 + j] = u0.s[dd];
            lvt[(d0 + 8 + dd) * 264 + j] = u1.s[dd];
        }
    }

    const int l = tid & 63, wv = tid >> 6;
    const int lr = l & 15, lg = l >> 4;
    const int qrow = half * 128 + wv * 16 + lr;   // this lane's q row (within window)

    // Q fragment straight from global (each wave owns 16 q rows)
    bf16x8 bq = *(const bf16x8*)(qkv + ((size_t)(w * 256 + qrow) * 3 + 0) * 192 + h * 32 + lg * 8);

    __syncthreads();

    const f32x4 zero = {0.f, 0.f, 0.f, 0.f};

    // S^T = K Q^T : A = K-tile nt (16 kv rows), B = Q (this wave's 16 q rows)
    f32x4 s[16];
#pragma unroll
    for (int nt = 0; nt < 16; ++nt) {
        bf16x8 ak = *(const bf16x8*)&lk[(nt * 16 + lr) * 40 + lg * 8];
        s[nt] = __builtin_amdgcn_mfma_f32_16x16x32_bf16(ak, bq, zero, 0, 0, 0);
    }

    // bias add (vectorized float4 per lane) + softmax over kv (per-lane 64 vals + 2 shuffles)
    const float* mrow = mask + (size_t)w * 65536 + (size_t)qrow * 256;
    const float* brow = rpb + (size_t)h * 65536 + (size_t)qrow * 256;
    float mx = -1e30f;
#pragma unroll
    for (int nt = 0; nt < 16; ++nt) {
        float4 mv = *(const float4*)(mrow + nt * 16 + lg * 4);
        float4 bv = *(const float4*)(brow + nt * 16 + lg * 4);
        s[nt][0] += mv.x + bv.x;
        s[nt][1] += mv.y + bv.y;
        s[nt][2] += mv.z + bv.z;
        s[nt][3] += mv.w + bv.w;
#pragma unroll
        for (int j = 0; j < 4; ++j) mx = fmaxf(mx, s[nt][j]);
    }
    mx = fmaxf(mx, __shfl_xor(mx, 16));
    mx = fmaxf(mx, __shfl_xor(mx, 32));
    float sum = 0.f;
#pragma unroll
    for (int nt = 0; nt < 16; ++nt)
#pragma unroll
        for (int j = 0; j < 4; ++j) {
            float e = __expf(s[nt][j] - mx);
            s[nt][j] = e;
            sum += e;
        }
    sum += __shfl_xor(sum, 16);
    sum += __shfl_xor(sum, 32);

    // O = P V, kv chunks of 32, per-wave LDS transpose of P (S^T regs -> q-row-major)
    f32x4 o[2] = {};
    u16* pb = lp + wv * 640;
#pragma unroll
    for (int c = 0; c < 8; ++c) {
#pragma unroll
        for (int t = 0; t < 2; ++t) {
            int nt = 2 * c + t;
            ushort4 o4;
            o4.x = f2b(s[nt][0]);
            o4.y = f2b(s[nt][1]);
            o4.z = f2b(s[nt][2]);
            o4.w = f2b(s[nt][3]);
            *(ushort4*)&pb[lr * 40 + t * 16 + lg * 4] = o4;
        }
        bf16x8 ap = *(const bf16x8*)&pb[lr * 40 + lg * 8];
#pragma unroll
        for (int dt = 0; dt < 2; ++dt) {
            bf16x8 bv = *(const bf16x8*)&lvt[(dt * 16 + lr) * 264 + c * 32 + lg * 8];
            o[dt] = __builtin_amdgcn_mfma_f32_16x16x32_bf16(ap, bv, o[dt], 0, 0, 0);
        }
    }

    // normalize (denominators live at lanes 0..15) + store bf16
    float rinv[4];
#pragma unroll
    for (int j = 0; j < 4; ++j) rinv[j] = 1.0f / __shfl(sum, lg * 4 + j);
#pragma unroll
    for (int dt = 0; dt < 2; ++dt)
#pragma unroll
        for (int j = 0; j < 4; ++j) {
            int i = half * 128 + wv * 16 + lg * 4 + j;
            float v = o[dt][j] * rinv[j];
            out[((size_t)(w * 256 + i)) * 192 + h * 32 + dt * 16 + lr] = f2b(v);
        }
}

extern "C" void kernel_launch(void* const* d_in, const int* in_sizes, int n_in,
                              void* d_out, int out_size, void* d_ws, size_t ws_size,
                              hipStream_t stream) {
    const float* x      = (const float*)d_in[0];
    const int*   rpi    = (const int*)d_in[1];
    const float* mask   = (const float*)d_in[2];
    const float* qkv_w  = (const float*)d_in[3];
    const float* qkv_b  = (const float*)d_in[4];
    const float* proj_w = (const float*)d_in[5];
    const float* proj_b = (const float*)d_in[6];
    const float* table  = (const float*)d_in[7];

    char* p = (char*)d_ws;
    u16* xb   = (u16*)p;  p += (size_t)65536 * 192 * 2;  // x bf16; later reused as attn_out
    u16* qkvb = (u16*)p;  p += (size_t)65536 * 576 * 2;  // qkv bf16 [w][i][3][h][d]
    u16* wtq  = (u16*)p;  p += (size_t)576 * 192 * 2;    // qkv_w^T bf16 [576][192]
    u16* wtp  = (u16*)p;  p += (size_t)192 * 192 * 2;    // proj_w^T bf16 [192][192]
    float* rpb = (float*)p; p += (size_t)6 * 65536 * 4;  // [6][256][256]

    hipLaunchKernelGGL(cast_f32_to_bf16_vec, dim3(2048), dim3(256), 0, stream,
                       x, xb, 65536 * 192 / 4);
    hipLaunchKernelGGL(cast_transpose, dim3((576 * 192 + 255) / 256), dim3(256), 0, stream,
                       qkv_w, wtq, 576, 192);
    hipLaunchKernelGGL(cast_transpose, dim3((192 * 192 + 255) / 256), dim3(256), 0, stream,
                       proj_w, wtp, 192, 192);
    hipLaunchKernelGGL(rpb_gather, dim3(256), dim3(256), 0, stream, rpi, table, rpb);

    const float qscale = 0.17677669529663687f;  // 1/sqrt(32)
    hipLaunchKernelGGL((gemm_k<true>), dim3(512, 9), dim3(512), 0, stream,
                       xb, wtq, qkv_b, (void*)qkvb, 576, qscale);
    hipLaunchKernelGGL(attn_k, dim3(3072), dim3(512), 0, stream, qkvb, rpb, mask, xb);
    hipLaunchKernelGGL((gemm_k<false>), dim3(512, 3), dim3(512), 0, stream,
                       xb, wtp, proj_b, d_out, 192, 1.0f);
}

// Round 3
// 190.639 us; speedup vs baseline: 1.1893x; 1.1893x over previous
//
#include <hip/hip_runtime.h>
#include <hip/hip_bf16.h>

typedef short bf16x8 __attribute__((ext_vector_type(8)));
typedef float f32x4 __attribute__((ext_vector_type(4)));
typedef unsigned short u16;
typedef unsigned int u32;

__device__ __forceinline__ u16 f2b(float v) {
    u32 u = __float_as_uint(v);
    u += 0x7fff + ((u >> 16) & 1);   // round-to-nearest-even
    return (u16)(u >> 16);
}

__device__ __forceinline__ void gload16(const void* g, void* l) {
    __builtin_amdgcn_global_load_lds(
        (const __attribute__((address_space(1))) u32*)g,
        (__attribute__((address_space(3))) u32*)l, 16, 0, 0);
}

// ---------------- prep kernels ----------------
__global__ void cast_f32_to_bf16_vec(const float* __restrict__ in, u16* __restrict__ out, int n4) {
    int i = blockIdx.x * blockDim.x + threadIdx.x;
    int stride = gridDim.x * blockDim.x;
    for (; i < n4; i += stride) {
        float4 v = ((const float4*)in)[i];
        ushort4 o;
        o.x = f2b(v.x); o.y = f2b(v.y); o.z = f2b(v.z); o.w = f2b(v.w);
        ((ushort4*)out)[i] = o;
    }
}

// wt[n*K + k] = w[k*N + n]  (f32 -> bf16)
__global__ void cast_transpose(const float* __restrict__ w, u16* __restrict__ wt, int N, int K) {
    int i = blockIdx.x * blockDim.x + threadIdx.x;
    if (i >= N * K) return;
    int n = i / K, k = i - n * K;
    wt[i] = f2b(w[(size_t)k * N + n]);
}

// rpb[h][i][j] = table[rpi[i][j]*6 + h]
__global__ void rpb_gather(const int* __restrict__ rpi, const float* __restrict__ table,
                           float* __restrict__ rpb) {
    int ij = blockIdx.x * blockDim.x + threadIdx.x;  // 65536
    int idx = rpi[ij];
#pragma unroll
    for (int h = 0; h < 6; ++h) rpb[h * 65536 + ij] = table[idx * 6 + h];
}

// ---------------- GEMM: C[M][N] = A[M][192] * Bt[N][192]^T ----------------
// BM=128, BN=64, 8 waves (4x2), wave tile 32x32, full K staged in LDS.
// IS_QKV epilogue routes to head-major qb/kb and transposed vtb.
template <bool IS_QKV>
__global__ __launch_bounds__(512) void gemm_k(const u16* __restrict__ A, const u16* __restrict__ Bt,
                                              const float* __restrict__ bias, void* o0, void* o1,
                                              void* o2, float qscale) {
    __shared__ u16 lsA[128 * 200];
    __shared__ u16 lsB[64 * 200];
    const int m0 = blockIdx.x * 128;
    const int n0 = blockIdx.y * 64;
    const int tid = threadIdx.x;

    for (int c = tid; c < 128 * 24; c += 512) {
        int r = c / 24, cc = c % 24;
        *(uint4*)&lsA[r * 200 + cc * 8] = *(const uint4*)(A + (size_t)(m0 + r) * 192 + cc * 8);
    }
    for (int c = tid; c < 64 * 24; c += 512) {
        int r = c / 24, cc = c % 24;
        *(uint4*)&lsB[r * 200 + cc * 8] = *(const uint4*)(Bt + (size_t)(n0 + r) * 192 + cc * 8);
    }
    __syncthreads();

    const int l = tid & 63, wv = tid >> 6;
    const int wm = wv >> 1, wn = wv & 1;
    const int lr = l & 15, lg = l >> 4;

    f32x4 acc[2][2] = {};
#pragma unroll
    for (int ks = 0; ks < 6; ++ks) {
        bf16x8 a[2], b[2];
#pragma unroll
        for (int i = 0; i < 2; ++i)
            a[i] = *(const bf16x8*)&lsA[(wm * 32 + i * 16 + lr) * 200 + ks * 32 + lg * 8];
#pragma unroll
        for (int i = 0; i < 2; ++i)
            b[i] = *(const bf16x8*)&lsB[(wn * 32 + i * 16 + lr) * 200 + ks * 32 + lg * 8];
#pragma unroll
        for (int m = 0; m < 2; ++m)
#pragma unroll
            for (int n = 0; n < 2; ++n)
                acc[m][n] = __builtin_amdgcn_mfma_f32_16x16x32_bf16(a[m], b[n], acc[m][n], 0, 0, 0);
    }

#pragma unroll
    for (int m = 0; m < 2; ++m)
#pragma unroll
        for (int n = 0; n < 2; ++n)
#pragma unroll
            for (int j = 0; j < 4; ++j) {
                int gr = m0 + wm * 32 + m * 16 + lg * 4 + j;
                int gc = n0 + wn * 32 + n * 16 + lr;
                float v = acc[m][n][j] + bias[gc];
                if (IS_QKV) {
                    int wq = gr >> 8, ii = gr & 255;
                    int mat = gc / 192;
                    int rem = gc - mat * 192;
                    int hh = rem >> 5, dd = rem & 31;
                    size_t w6h = (size_t)(wq * 6 + hh);
                    if (mat == 0)
                        ((u16*)o0)[(w6h * 256 + ii) * 32 + dd] = f2b(v * qscale);
                    else if (mat == 1)
                        ((u16*)o1)[(w6h * 256 + ii) * 32 + dd] = f2b(v);
                    else
                        ((u16*)o2)[w6h * 8192 + (size_t)dd * 256 + ii] = f2b(v);
                } else {
                    ((float*)o0)[(size_t)gr * 192 + gc] = v;
                }
            }
}

// ---------------- attention ----------------
// block = (window, q-half), 8 waves x 16 q-rows, loop over 6 heads.
// S^T layout: mfma(A=K, B=Q) -> lane owns q = lr; kv = nt*16 + lg*4 + j.
// Streaming: no max-subtraction (scores bounded ~|7|), QK->exp->PV per 32-kv chunk.
__global__ __launch_bounds__(512, 4) void attn_k(const u16* __restrict__ qb,
                                                 const u16* __restrict__ kb,
                                                 const u16* __restrict__ vtb,
                                                 const float* __restrict__ rpb,
                                                 const float* __restrict__ mask,
                                                 u16* __restrict__ out) {
    __shared__ u16 lk[2][256 * 32];   // K rows, linear stride 32 (uniform banks for b128)
    __shared__ u16 lvt[2][32 * 256];  // V^T rows [d][np], linear + XOR-swizzled content
    __shared__ u16 lp[8 * 640];       // per-wave P chunk [16 q][40]

    const int bid = blockIdx.x;
    const int xcd = bid & 7, idx = bid >> 3;
    const int w = xcd * 32 + (idx >> 1), half = idx & 1;
    const int tid = threadIdx.x;
    const int l = tid & 63, wv = tid >> 6;
    const int lr = l & 15, lg = l >> 4;
    const int qrow = half * 128 + wv * 16 + lr;

    // stage head 0 (async DMA; V source pre-swizzled so linear LDS == swizzled layout)
    {
        const u16* ks = kb + (size_t)(w * 6 + 0) * 8192;
        const u16* vs = vtb + (size_t)(w * 6 + 0) * 8192;
        for (int c = tid; c < 1024; c += 512) {
            gload16(ks + c * 8, &lk[0][c * 8]);
            u32 so = (u32)(c * 16) ^ ((((u32)c >> 5) & 7) << 4);
            gload16((const char*)vs + so, &lvt[0][c * 8]);
        }
    }
    bf16x8 bq_n = *(const bf16x8*)(qb + ((size_t)(w * 6 + 0) * 256 + qrow) * 32 + lg * 8);
    __syncthreads();  // drains vmcnt -> head 0 staged

    const float* mrow = mask + (size_t)w * 65536 + (size_t)qrow * 256;
    u16* pb = lp + wv * 640;

    for (int h = 0; h < 6; ++h) {
        const int cur = h & 1, nxt = cur ^ 1;
        if (h < 5) {  // prefetch next head into other buffer (lands by end-of-head barrier)
            const u16* ks = kb + (size_t)(w * 6 + h + 1) * 8192;
            const u16* vs = vtb + (size_t)(w * 6 + h + 1) * 8192;
            for (int c = tid; c < 1024; c += 512) {
                gload16(ks + c * 8, &lk[nxt][c * 8]);
                u32 so = (u32)(c * 16) ^ ((((u32)c >> 5) & 7) << 4);
                gload16((const char*)vs + so, &lvt[nxt][c * 8]);
            }
        }
        bf16x8 bq = bq_n;
        if (h < 5)
            bq_n = *(const bf16x8*)(qb + ((size_t)(w * 6 + h + 1) * 256 + qrow) * 32 + lg * 8);

        const float* brow = rpb + (size_t)h * 65536 + (size_t)qrow * 256;
        const f32x4 zero = {0.f, 0.f, 0.f, 0.f};
        f32x4 o[2] = {};
        float sum = 0.f;

#pragma unroll
        for (int c = 0; c < 8; ++c) {
            // QK^T for 32 kv cols
            f32x4 s[2];
#pragma unroll
            for (int t = 0; t < 2; ++t) {
                int nt = 2 * c + t;
                bf16x8 ak = *(const bf16x8*)&lk[cur][(nt * 16 + lr) * 32 + lg * 8];
                s[t] = __builtin_amdgcn_mfma_f32_16x16x32_bf16(ak, bq, zero, 0, 0, 0);
            }
            // bias + exp (no max subtraction), accumulate denominator
#pragma unroll
            for (int t = 0; t < 2; ++t) {
                int nt = 2 * c + t;
                float4 mv = *(const float4*)(mrow + nt * 16 + lg * 4);
                float4 bv = *(const float4*)(brow + nt * 16 + lg * 4);
                s[t][0] = __expf(s[t][0] + mv.x + bv.x);
                s[t][1] = __expf(s[t][1] + mv.y + bv.y);
                s[t][2] = __expf(s[t][2] + mv.z + bv.z);
                s[t][3] = __expf(s[t][3] + mv.w + bv.w);
                sum += (s[t][0] + s[t][1]) + (s[t][2] + s[t][3]);
                ushort4 o4;
                o4.x = f2b(s[t][0]); o4.y = f2b(s[t][1]);
                o4.z = f2b(s[t][2]); o4.w = f2b(s[t][3]);
                *(ushort4*)&pb[lr * 40 + t * 16 + lg * 4] = o4;
            }
            // PV for this chunk
            bf16x8 ap = *(const bf16x8*)&pb[lr * 40 + lg * 8];
#pragma unroll
            for (int dt = 0; dt < 2; ++dt) {
                int ui = ((dt * 16 + lr) * 256 + c * 32 + lg * 8) ^ ((lr & 7) << 3);
                bf16x8 bv2 = *(const bf16x8*)&lvt[cur][ui];
                o[dt] = __builtin_amdgcn_mfma_f32_16x16x32_bf16(ap, bv2, o[dt], 0, 0, 0);
            }
        }

        sum += __shfl_xor(sum, 16);
        sum += __shfl_xor(sum, 32);
        float rinv[4];
#pragma unroll
        for (int j = 0; j < 4; ++j) rinv[j] = 1.0f / __shfl(sum, lg * 4 + j);
#pragma unroll
        for (int dt = 0; dt < 2; ++dt)
#pragma unroll
            for (int j = 0; j < 4; ++j) {
                int i = half * 128 + wv * 16 + lg * 4 + j;
                out[((size_t)(w * 256 + i)) * 192 + h * 32 + dt * 16 + lr] =
                    f2b(o[dt][j] * rinv[j]);
            }
        __syncthreads();  // next-head staging landed; cur buffers free for h+2 prefetch
    }
}

extern "C" void kernel_launch(void* const* d_in, const int* in_sizes, int n_in,
                              void* d_out, int out_size, void* d_ws, size_t ws_size,
                              hipStream_t stream) {
    const float* x      = (const float*)d_in[0];
    const int*   rpi    = (const int*)d_in[1];
    const float* mask   = (const float*)d_in[2];
    const float* qkv_w  = (const float*)d_in[3];
    const float* qkv_b  = (const float*)d_in[4];
    const float* proj_w = (const float*)d_in[5];
    const float* proj_b = (const float*)d_in[6];
    const float* table  = (const float*)d_in[7];

    char* p = (char*)d_ws;
    u16* xb   = (u16*)p;  p += (size_t)65536 * 192 * 2;  // x bf16; later reused as attn_out
    u16* qb   = (u16*)p;  p += (size_t)65536 * 192 * 2;  // Q  [w][h][i][d] bf16 (pre-scaled)
    u16* kb   = (u16*)p;  p += (size_t)65536 * 192 * 2;  // K  [w][h][i][d] bf16
    u16* vtb  = (u16*)p;  p += (size_t)65536 * 192 * 2;  // V^T [w][h][d][i] bf16
    u16* wtq  = (u16*)p;  p += (size_t)576 * 192 * 2;    // qkv_w^T bf16
    u16* wtp  = (u16*)p;  p += (size_t)192 * 192 * 2;    // proj_w^T bf16
    float* rpb = (float*)p; p += (size_t)6 * 65536 * 4;  // [6][256][256]

    hipLaunchKernelGGL(cast_f32_to_bf16_vec, dim3(2048), dim3(256), 0, stream,
                       x, xb, 65536 * 192 / 4);
    hipLaunchKernelGGL(cast_transpose, dim3((576 * 192 + 255) / 256), dim3(256), 0, stream,
                       qkv_w, wtq, 576, 192);
    hipLaunchKernelGGL(cast_transpose, dim3((192 * 192 + 255) / 256), dim3(256), 0, stream,
                       proj_w, wtp, 192, 192);
    hipLaunchKernelGGL(rpb_gather, dim3(256), dim3(256), 0, stream, rpi, table, rpb);

    const float qscale = 0.17677669529663687f;  // 1/sqrt(32)
    hipLaunchKernelGGL((gemm_k<true>), dim3(512, 9), dim3(512), 0, stream,
                       xb, wtq, qkv_b, (void*)qb, (void*)kb, (void*)vtb, qscale);
    hipLaunchKernelGGL(attn_k, dim3(512), dim3(512), 0, stream, qb, kb, vtb, rpb, mask, xb);
    hipLaunchKernelGGL((gemm_k<false>), dim3(512, 3), dim3(512), 0, stream,
                       xb, wtp, proj_b, d_out, nullptr, nullptr, 1.0f);
}

// Round 6
// 183.888 us; speedup vs baseline: 1.2330x; 1.0367x over previous
//
#include <hip/hip_runtime.h>
#include <hip/hip_bf16.h>

typedef short bf16x8 __attribute__((ext_vector_type(8)));
typedef float f32x4 __attribute__((ext_vector_type(4)));
typedef unsigned short u16;
typedef unsigned int u32;

__device__ __forceinline__ u16 f2b(float v) {
    u32 u = __float_as_uint(v);
    u += 0x7fff + ((u >> 16) & 1);   // round-to-nearest-even
    return (u16)(u >> 16);
}

__device__ __forceinline__ u32 cvtpk(float lo, float hi) {
    u32 r;
    asm("v_cvt_pk_bf16_f32 %0, %1, %2" : "=v"(r) : "v"(lo), "v"(hi));
    return r;
}

__device__ __forceinline__ void gload16(const void* g, void* l) {
    __builtin_amdgcn_global_load_lds(
        (const __attribute__((address_space(1))) u32*)g,
        (__attribute__((address_space(3))) u32*)l, 16, 0, 0);
}

// ---------------- prep kernels ----------------
__global__ void cast_f32_to_bf16_vec(const float* __restrict__ in, u16* __restrict__ out, int n4) {
    int i = blockIdx.x * blockDim.x + threadIdx.x;
    int stride = gridDim.x * blockDim.x;
    for (; i < n4; i += stride) {
        float4 v = ((const float4*)in)[i];
        ushort4 o;
        o.x = f2b(v.x); o.y = f2b(v.y); o.z = f2b(v.z); o.w = f2b(v.w);
        ((ushort4*)out)[i] = o;
    }
}

// wt[n*K + k] = w[k*N + n]  (f32 -> bf16)
__global__ void cast_transpose(const float* __restrict__ w, u16* __restrict__ wt, int N, int K) {
    int i = blockIdx.x * blockDim.x + threadIdx.x;
    if (i >= N * K) return;
    int n = i / K, k = i - n * K;
    wt[i] = f2b(w[(size_t)k * N + n]);
}

// rpb[h][i][j] = table[rpi[i][j]*6 + h]
__global__ void rpb_gather(const int* __restrict__ rpi, const float* __restrict__ table,
                           float* __restrict__ rpb) {
    int ij = blockIdx.x * blockDim.x + threadIdx.x;  // 65536
    int idx = rpi[ij];
#pragma unroll
    for (int h = 0; h < 6; ++h) rpb[h * 65536 + ij] = table[idx * 6 + h];
}

// ---------------- QKV GEMM: A[65536][192] x Bt[576][192]^T ----------------
// BM=128 (512 blocks), A in registers (wave owns 16 rows), loop 9 N-tiles
// of 64 cols with double-buffered async B staging (source-swizzled, linear LDS).
__global__ __launch_bounds__(512, 4) void qkv_gemm(const u16* __restrict__ A,
                                                   const u16* __restrict__ Bt,
                                                   const float* __restrict__ bias,
                                                   u16* __restrict__ qb, u16* __restrict__ kb,
                                                   u16* __restrict__ vtb, float qscale) {
    __shared__ u16 lsB[2][64 * 192];
    const int m0 = blockIdx.x * 128;
    const int tid = threadIdx.x;
    const int l = tid & 63, wv = tid >> 6;
    const int lr = l & 15, lg = l >> 4;

    // A fragments: rows m0 + wv*16 + lr, k = ks*32 + lg*8
    bf16x8 areg[6];
#pragma unroll
    for (int ks = 0; ks < 6; ++ks)
        areg[ks] = *(const bf16x8*)(A + (size_t)(m0 + wv * 16 + lr) * 192 + ks * 32 + lg * 8);

    // stage: 64 rows x 24 chunks(16B); LDS chunk (r,m) <- global chunk (r, m^(r&7) low3)
#define STAGE_B(tile, buf)                                                      \
    {                                                                           \
        const u16* src = Bt + (size_t)(tile) * 64 * 192;                        \
        for (int c = tid; c < 1536; c += 512) {                                 \
            int r = c / 24, mc = c - r * 24;                                    \
            int gsw = (mc & ~7) | ((mc ^ r) & 7);                               \
            gload16(src + (r * 24 + gsw) * 8, &lsB[buf][c * 8]);                \
        }                                                                       \
    }
    STAGE_B(0, 0);
    __syncthreads();

    const int wq = m0 >> 8;           // window
    const int ibase = (blockIdx.x & 1) * 128 + wv * 16 + lg * 4;

    for (int n0 = 0; n0 < 9; ++n0) {
        const int cur = n0 & 1;
        if (n0 < 8) STAGE_B(n0 + 1, cur ^ 1);

        f32x4 acc[4] = {};
#pragma unroll
        for (int ks = 0; ks < 6; ++ks) {
            int cidx = ks * 4 + lg;
            int csw = (cidx & ~7) | ((cidx ^ lr) & 7);
#pragma unroll
            for (int bn = 0; bn < 4; ++bn) {
                bf16x8 b = *(const bf16x8*)&lsB[cur][(bn * 16 + lr) * 192 + csw * 8];
                acc[bn] = __builtin_amdgcn_mfma_f32_16x16x32_bf16(areg[ks], b, acc[bn], 0, 0, 0);
            }
        }
        __syncthreads();   // B[cur] reads done by all waves; nxt staged

        // epilogue: this tile's 64 cols lie in one matrix: mat = n0/3
        const int mat = n0 / 3;
        const int base = (n0 - mat * 3) * 64;
#pragma unroll
        for (int bn = 0; bn < 4; ++bn)
#pragma unroll
            for (int j = 0; j < 4; ++j) {
                int ii = ibase + j;
                int rem = base + bn * 16 + lr;
                int hh = rem >> 5, dd = rem & 31;
                size_t w6h = (size_t)(wq * 6 + hh);
                float v = acc[bn][j] + bias[mat * 192 + rem];
                if (mat == 0)
                    qb[(w6h * 256 + ii) * 32 + dd] = f2b(v * qscale);
                else if (mat == 1)
                    kb[(w6h * 256 + ii) * 32 + dd] = f2b(v);
                else
                    vtb[w6h * 8192 + (size_t)dd * 256 + ii] = f2b(v);
            }
    }
}

// ---------------- proj GEMM: C[M][192] = A[M][192] * Bt[192][192]^T ----------------
__global__ __launch_bounds__(512) void proj_gemm(const u16* __restrict__ A,
                                                 const u16* __restrict__ Bt,
                                                 const float* __restrict__ bias,
                                                 float* __restrict__ out) {
    __shared__ u16 lsA[128 * 200];
    __shared__ u16 lsB[64 * 200];
    const int m0 = blockIdx.x * 128;
    const int n0 = blockIdx.y * 64;
    const int tid = threadIdx.x;

    for (int c = tid; c < 128 * 24; c += 512) {
        int r = c / 24, cc = c % 24;
        *(uint4*)&lsA[r * 200 + cc * 8] = *(const uint4*)(A + (size_t)(m0 + r) * 192 + cc * 8);
    }
    for (int c = tid; c < 64 * 24; c += 512) {
        int r = c / 24, cc = c % 24;
        *(uint4*)&lsB[r * 200 + cc * 8] = *(const uint4*)(Bt + (size_t)(n0 + r) * 192 + cc * 8);
    }
    __syncthreads();

    const int l = tid & 63, wv = tid >> 6;
    const int wm = wv >> 1, wn = wv & 1;
    const int lr = l & 15, lg = l >> 4;

    f32x4 acc[2][2] = {};
#pragma unroll
    for (int ks = 0; ks < 6; ++ks) {
        bf16x8 a[2], b[2];
#pragma unroll
        for (int i = 0; i < 2; ++i)
            a[i] = *(const bf16x8*)&lsA[(wm * 32 + i * 16 + lr) * 200 + ks * 32 + lg * 8];
#pragma unroll
        for (int i = 0; i < 2; ++i)
            b[i] = *(const bf16x8*)&lsB[(wn * 32 + i * 16 + lr) * 200 + ks * 32 + lg * 8];
#pragma unroll
        for (int m = 0; m < 2; ++m)
#pragma unroll
            for (int n = 0; n < 2; ++n)
                acc[m][n] = __builtin_amdgcn_mfma_f32_16x16x32_bf16(a[m], b[n], acc[m][n], 0, 0, 0);
    }

#pragma unroll
    for (int m = 0; m < 2; ++m)
#pragma unroll
        for (int n = 0; n < 2; ++n)
#pragma unroll
            for (int j = 0; j < 4; ++j) {
                int gr = m0 + wm * 32 + m * 16 + lg * 4 + j;
                int gc = n0 + wn * 32 + n * 16 + lr;
                out[(size_t)gr * 192 + gc] = acc[m][n][j] + bias[gc];
            }
}

// ---------------- attention ----------------
// block = (window, q-half), 8 waves x 16 q-rows, loop over 6 heads.
// S^T layout: mfma(A=K, B=Q) -> lane owns q = lr; kv = nt*16 + lg*4 + j.
// Streaming: no max-subtraction (scores bounded), QK->exp->PV per 32-kv chunk.
// K LDS: linear stride-32 rows, chunk-swizzled via source address.
// V^T read swizzle: XOR the FULL element index (carry-free) — r4's hoisted form
// added c*32 after the XOR and carried into the chunk index (the r4 bug).
__global__ __launch_bounds__(512, 4) void attn_k(const u16* __restrict__ qb,
                                                 const u16* __restrict__ kb,
                                                 const u16* __restrict__ vtb,
                                                 const float* __restrict__ rpb,
                                                 const float* __restrict__ mask,
                                                 u16* __restrict__ out) {
    __shared__ u16 lk[2][256 * 32];   // K rows (swizzled content, linear layout)
    __shared__ u16 lvt[2][32 * 256];  // V^T rows (swizzled content)
    __shared__ u16 lp[8 * 640];       // per-wave P chunk [16 q][40]

    const int bid = blockIdx.x;
    const int xcd = bid & 7, idx = bid >> 3;
    const int w = xcd * 32 + (idx >> 1), half = idx & 1;
    const int tid = threadIdx.x;
    const int l = tid & 63, wv = tid >> 6;
    const int lr = l & 15, lg = l >> 4;
    const int qrow = half * 128 + wv * 16 + lr;

#define STAGE_KV(hh, buf)                                                        \
    {                                                                            \
        const u16* ks = kb + (size_t)(w * 6 + (hh)) * 8192;                      \
        const u16* vs = vtb + (size_t)(w * 6 + (hh)) * 8192;                     \
        for (int c = tid; c < 1024; c += 512) {                                  \
            int r = c >> 2;                                                      \
            int gsw = (c & ~3) | ((c ^ (r >> 1)) & 3);                           \
            gload16(ks + gsw * 8, &lk[buf][c * 8]);                              \
            u32 so = (u32)(c * 16) ^ ((((u32)c >> 5) & 7) << 4);                 \
            gload16((const char*)vs + so, &lvt[buf][c * 8]);                     \
        }                                                                        \
    }

    STAGE_KV(0, 0);
    bf16x8 bq_n = *(const bf16x8*)(qb + ((size_t)(w * 6 + 0) * 256 + qrow) * 32 + lg * 8);
    __syncthreads();  // head 0 staged

    const float* mrow = mask + (size_t)w * 65536 + (size_t)qrow * 256;
    u16* pb = lp + wv * 640;
    const int koff = lr * 32 + (lg ^ ((lr >> 1) & 3)) * 8;        // swizzled K read offset

    for (int h = 0; h < 6; ++h) {
        const int cur = h & 1, nxt = cur ^ 1;
        if (h < 5) STAGE_KV(h + 1, nxt);
        bf16x8 bq = bq_n;
        if (h < 5)
            bq_n = *(const bf16x8*)(qb + ((size_t)(w * 6 + h + 1) * 256 + qrow) * 32 + lg * 8);

        const float* brow = rpb + (size_t)h * 65536 + (size_t)qrow * 256;
        const f32x4 zero = {0.f, 0.f, 0.f, 0.f};
        f32x4 o[2] = {};
        float sum = 0.f;

        // bias pipeline: preload chunk 0
        float4 pm0 = *(const float4*)(mrow + lg * 4);
        float4 pm1 = *(const float4*)(mrow + 16 + lg * 4);
        float4 pq0 = *(const float4*)(brow + lg * 4);
        float4 pq1 = *(const float4*)(brow + 16 + lg * 4);

#pragma unroll
        for (int c = 0; c < 8; ++c) {
            // QK^T for 32 kv cols
            bf16x8 ak0 = *(const bf16x8*)&lk[cur][(2 * c) * 512 + koff];
            bf16x8 ak1 = *(const bf16x8*)&lk[cur][(2 * c + 1) * 512 + koff];
            f32x4 s0 = __builtin_amdgcn_mfma_f32_16x16x32_bf16(ak0, bq, zero, 0, 0, 0);
            f32x4 s1 = __builtin_amdgcn_mfma_f32_16x16x32_bf16(ak1, bq, zero, 0, 0, 0);

            // prefetch next chunk's bias while MFMA/exp run
            float4 nm0, nm1, nq0, nq1;
            if (c < 7) {
                nm0 = *(const float4*)(mrow + (2 * c + 2) * 16 + lg * 4);
                nm1 = *(const float4*)(mrow + (2 * c + 3) * 16 + lg * 4);
                nq0 = *(const float4*)(brow + (2 * c + 2) * 16 + lg * 4);
                nq1 = *(const float4*)(brow + (2 * c + 3) * 16 + lg * 4);
            }

            s0[0] = __expf(s0[0] + pm0.x + pq0.x);
            s0[1] = __expf(s0[1] + pm0.y + pq0.y);
            s0[2] = __expf(s0[2] + pm0.z + pq0.z);
            s0[3] = __expf(s0[3] + pm0.w + pq0.w);
            s1[0] = __expf(s1[0] + pm1.x + pq1.x);
            s1[1] = __expf(s1[1] + pm1.y + pq1.y);
            s1[2] = __expf(s1[2] + pm1.z + pq1.z);
            s1[3] = __expf(s1[3] + pm1.w + pq1.w);
            sum += ((s0[0] + s0[1]) + (s0[2] + s0[3])) + ((s1[0] + s1[1]) + (s1[2] + s1[3]));

            uint2 w0, w1;
            w0.x = cvtpk(s0[0], s0[1]); w0.y = cvtpk(s0[2], s0[3]);
            w1.x = cvtpk(s1[0], s1[1]); w1.y = cvtpk(s1[2], s1[3]);
            *(uint2*)&pb[lr * 40 + lg * 4] = w0;
            *(uint2*)&pb[lr * 40 + 16 + lg * 4] = w1;

            bf16x8 ap = *(const bf16x8*)&pb[lr * 40 + lg * 8];
            // carry-free: XOR applied to the complete element index
            int vi0 = (lr * 256 + c * 32 + lg * 8) ^ ((lr & 7) << 3);
            int vi1 = ((16 + lr) * 256 + c * 32 + lg * 8) ^ ((lr & 7) << 3);
            bf16x8 bv0 = *(const bf16x8*)&lvt[cur][vi0];
            bf16x8 bv1 = *(const bf16x8*)&lvt[cur][vi1];
            o[0] = __builtin_amdgcn_mfma_f32_16x16x32_bf16(ap, bv0, o[0], 0, 0, 0);
            o[1] = __builtin_amdgcn_mfma_f32_16x16x32_bf16(ap, bv1, o[1], 0, 0, 0);

            if (c < 7) { pm0 = nm0; pm1 = nm1; pq0 = nq0; pq1 = nq1; }
        }

        sum += __shfl_xor(sum, 16);
        sum += __shfl_xor(sum, 32);
        float rinv[4];
#pragma unroll
        for (int j = 0; j < 4; ++j) rinv[j] = __builtin_amdgcn_rcpf(__shfl(sum, lg * 4 + j));
#pragma unroll
        for (int dt = 0; dt < 2; ++dt)
#pragma unroll
            for (int j = 0; j < 4; ++j) {
                int i = half * 128 + wv * 16 + lg * 4 + j;
                out[((size_t)(w * 256 + i)) * 192 + h * 32 + dt * 16 + lr] =
                    f2b(o[dt][j] * rinv[j]);
            }
        __syncthreads();  // next-head staging landed; cur buffers free
    }
}

extern "C" void kernel_launch(void* const* d_in, const int* in_sizes, int n_in,
                              void* d_out, int out_size, void* d_ws, size_t ws_size,
                              hipStream_t stream) {
    const float* x      = (const float*)d_in[0];
    const int*   rpi    = (const int*)d_in[1];
    const float* mask   = (const float*)d_in[2];
    const float* qkv_w  = (const float*)d_in[3];
    const float* qkv_b  = (const float*)d_in[4];
    const float* proj_w = (const float*)d_in[5];
    const float* proj_b = (const float*)d_in[6];
    const float* table  = (const float*)d_in[7];

    char* p = (char*)d_ws;
    u16* xb   = (u16*)p;  p += (size_t)65536 * 192 * 2;  // x bf16; later reused as attn_out
    u16* qb   = (u16*)p;  p += (size_t)65536 * 192 * 2;  // Q  [w][h][i][d] bf16 (pre-scaled)
    u16* kb   = (u16*)p;  p += (size_t)65536 * 192 * 2;  // K  [w][h][i][d] bf16
    u16* vtb  = (u16*)p;  p += (size_t)65536 * 192 * 2;  // V^T [w][h][d][i] bf16
    u16* wtq  = (u16*)p;  p += (size_t)576 * 192 * 2;    // qkv_w^T bf16
    u16* wtp  = (u16*)p;  p += (size_t)192 * 192 * 2;    // proj_w^T bf16
    float* rpb = (float*)p; p += (size_t)6 * 65536 * 4;  // [6][256][256]

    hipLaunchKernelGGL(cast_f32_to_bf16_vec, dim3(2048), dim3(256), 0, stream,
                       x, xb, 65536 * 192 / 4);
    hipLaunchKernelGGL(cast_transpose, dim3((576 * 192 + 255) / 256), dim3(256), 0, stream,
                       qkv_w, wtq, 576, 192);
    hipLaunchKernelGGL(cast_transpose, dim3((192 * 192 + 255) / 256), dim3(256), 0, stream,
                       proj_w, wtp, 192, 192);
    hipLaunchKernelGGL(rpb_gather, dim3(256), dim3(256), 0, stream, rpi, table, rpb);

    const float qscale = 0.17677669529663687f;  // 1/sqrt(32)
    hipLaunchKernelGGL(qkv_gemm, dim3(512), dim3(512), 0, stream,
                       xb, wtq, qkv_b, qb, kb, vtb, qscale);
    hipLaunchKernelGGL(attn_k, dim3(512), dim3(512), 0, stream, qb, kb, vtb, rpb, mask, xb);
    hipLaunchKernelGGL(proj_gemm, dim3(512, 3), dim3(512), 0, stream,
                       xb, wtp, proj_b, (float*)d_out);
}